// Round 4
// baseline (385.942 us; speedup 1.0000x reference)
//
#include <hip/hip_runtime.h>

#define Bd 4
#define Cd 256
#define Hd 256
#define Wd 256
#define HW 65536
#define CM 64
#define KK 9
#define CG 32   // channels per wave in agg
#define CSTEP 64

// ---------------- Kernel A: 1x1 compression: comp[b,o,s] = sum_c x[b,c,s]*w_comp[o,c]
// Round 3 post-mortem: no spill, scalar weights OK, but VALUBusy 33% — staging
// serialized behind barriers and only 128 FMA-cycles per cc-step of overhead.
// Round 4: 2 s-positions/thread (float2 acc[16], static indexing), ds_read_b64 LDS
// reads, and T14 async prefetch: next c0-tile global_loads issued before compute,
// ds_write after the barrier -> HBM latency hides under the FMA phase.
__global__ __launch_bounds__(256, 4) void compress_kernel(
    const float* __restrict__ x, const float* __restrict__ w_comp,
    float* __restrict__ comp)
{
    __shared__ float xs[CSTEP][128];   // 32 KiB: 64 channels x 128 s
    int tid = threadIdx.x;
    int sl  = tid & 63;        // lane: covers s pair 2*sl, 2*sl+1
    int og  = __builtin_amdgcn_readfirstlane(tid >> 6);   // wave-uniform o-group
    int blk = blockIdx.x;      // 2048 blocks: [b(4)][s-tile(512)]
    int b   = blk >> 9;
    int s0  = (blk & 511) << 7;

    const float* xb = x + (size_t)b * Cd * HW + s0;

    float2 acc[16];
#pragma unroll
    for (int k = 0; k < 16; ++k) acc[k] = make_float2(0.f, 0.f);

    float4 st[8];   // stage regs: 2048 float4 tile / 256 threads = 8 per thread
#pragma unroll
    for (int r = 0; r < 8; ++r) {
        int idx = r * 256 + tid;
        int cc  = idx >> 5;               // 0..63
        int ss  = (idx & 31) << 2;        // 0..124
        st[r] = *(const float4*)(xb + (size_t)cc * HW + ss);
    }

    for (int c0 = 0; c0 < Cd; c0 += CSTEP) {
        if (c0) __syncthreads();          // previous tile's readers done
#pragma unroll
        for (int r = 0; r < 8; ++r) {     // vmcnt(0) then ds_write_b128
            int idx = r * 256 + tid;
            int cc  = idx >> 5;
            int ss  = (idx & 31) << 2;
            *(float4*)&xs[cc][ss] = st[r];
        }
        if (c0 + CSTEP < Cd) {            // prefetch next tile; lands during compute
#pragma unroll
            for (int r = 0; r < 8; ++r) {
                int idx = r * 256 + tid;
                int cc  = idx >> 5;
                int ss  = (idx & 31) << 2;
                st[r] = *(const float4*)(xb + (size_t)(c0 + CSTEP + cc) * HW + ss);
            }
        }
        __syncthreads();                  // xs ready
        const float* wbase = w_comp + (og * 16) * Cd + c0;   // scalar address
#pragma unroll 1
        for (int cc = 0; cc < CSTEP; cc += 4) {
            float2 x0 = *(const float2*)&xs[cc + 0][sl * 2];
            float2 x1 = *(const float2*)&xs[cc + 1][sl * 2];
            float2 x2 = *(const float2*)&xs[cc + 2][sl * 2];
            float2 x3 = *(const float2*)&xs[cc + 3][sl * 2];
#pragma unroll
            for (int k = 0; k < 16; ++k) {
                const float* wr = wbase + k * Cd + cc;   // scalar -> s_load_dwordx4
                acc[k].x = fmaf(x0.x, wr[0], acc[k].x);
                acc[k].y = fmaf(x0.y, wr[0], acc[k].y);
                acc[k].x = fmaf(x1.x, wr[1], acc[k].x);
                acc[k].y = fmaf(x1.y, wr[1], acc[k].y);
                acc[k].x = fmaf(x2.x, wr[2], acc[k].x);
                acc[k].y = fmaf(x2.y, wr[2], acc[k].y);
                acc[k].x = fmaf(x3.x, wr[3], acc[k].x);
                acc[k].y = fmaf(x3.y, wr[3], acc[k].y);
            }
        }
    }
    float* ob = comp + (size_t)b * CM * HW + (size_t)(og * 16) * HW + s0 + sl * 2;
#pragma unroll
    for (int k = 0; k < 16; ++k)
        *(float2*)&ob[(size_t)k * HW] = acc[k];
}

// ---------------- Kernel B: 3x3 conv (zero pad) + bias + softmax over 9 taps
// One block = one (b,h) row; 4 waves cover 4 quarter-rows (lane-per-position).
// w_gen staged in LDS as wlds[c][t][12] (broadcast reads). Neighbors via shuffle.
__global__ __launch_bounds__(256) void kwgen_kernel(
    const float* __restrict__ comp, const float* __restrict__ w_gen,
    const float* __restrict__ b_gen, float* __restrict__ kw)
{
    __shared__ float wlds[CM][KK][12];
    // w_gen flat layout [t][c][3][3]: i = t*(CM*9) + c*9 + p
    for (int i = threadIdx.x; i < KK * CM * 9; i += 256) {
        int t = i / (CM * 9);
        int r = i - t * (CM * 9);
        int c = r / 9;
        int p = r - c * 9;
        wlds[c][t][p] = w_gen[i];
    }
    __syncthreads();

    int lane = threadIdx.x & 63;
    int q    = threadIdx.x >> 6;
    int b    = blockIdx.x >> 8;
    int h    = blockIdx.x & 255;
    int w    = q * 64 + lane;
    bool hmv = h > 0, hpv = h < Hd - 1;

    float acc[KK];
#pragma unroll
    for (int t = 0; t < KK; ++t) acc[t] = b_gen[t];

    const float* cb = comp + (size_t)b * CM * HW + h * Wd;
    for (int c = 0; c < CM; ++c) {
        const float* row = cb + (size_t)c * HW;
        float xm = hmv ? row[w - Wd] : 0.f;
        float xc = row[w];
        float xp = hpv ? row[w + Wd] : 0.f;
        float Lm = __shfl_up(xm, 1), Lc = __shfl_up(xc, 1), Lp = __shfl_up(xp, 1);
        float Rm = __shfl_down(xm, 1), Rc = __shfl_down(xc, 1), Rp = __shfl_down(xp, 1);
        if (lane == 0) {
            if (w == 0) { Lm = 0.f; Lc = 0.f; Lp = 0.f; }
            else {
                Lm = hmv ? row[w - 1 - Wd] : 0.f;
                Lc = row[w - 1];
                Lp = hpv ? row[w - 1 + Wd] : 0.f;
            }
        }
        if (lane == 63) {
            if (w == Wd - 1) { Rm = 0.f; Rc = 0.f; Rp = 0.f; }
            else {
                Rm = hmv ? row[w + 1 - Wd] : 0.f;
                Rc = row[w + 1];
                Rp = hpv ? row[w + 1 + Wd] : 0.f;
            }
        }
        float nb[9] = {Lm, xm, Rm, Lc, xc, Rc, Lp, xp, Rp};
#pragma unroll
        for (int t = 0; t < KK; ++t) {
            const float* wt = &wlds[c][t][0];
#pragma unroll
            for (int p = 0; p < 9; ++p)
                acc[t] = fmaf(nb[p], wt[p], acc[t]);
        }
    }
    // softmax over the 9 taps
    float m = acc[0];
#pragma unroll
    for (int t = 1; t < KK; ++t) m = fmaxf(m, acc[t]);
    float sum = 0.f;
#pragma unroll
    for (int t = 0; t < KK; ++t) { acc[t] = __expf(acc[t] - m); sum += acc[t]; }
    float inv = 1.f / sum;
    int s = h * Wd + w;
    float* ob = kw + (size_t)b * KK * HW + s;
#pragma unroll
    for (int t = 0; t < KK; ++t) ob[(size_t)t * HW] = acc[t] * inv;
}

// ---------------- Kernel C: view-scramble gather + hamming renorm + reflect aggregation
// Wave per (b, h, cgroup): lane covers 4 columns (float4); column neighbors via shuffle.
__global__ __launch_bounds__(256) void agg_kernel(
    const float* __restrict__ x, const float* __restrict__ kw,
    float* __restrict__ out)
{
    const float HAM[9] = {0.0064f, 0.08f, 0.0064f,
                          0.08f,   1.0f,  0.08f,
                          0.0064f, 0.08f, 0.0064f};
    int lane = threadIdx.x & 63;
    int wid  = threadIdx.x >> 6;
    int blk  = blockIdx.x;           // 2048 blocks: [b(4)][cg(8)][h4(64)]
    int h4 = blk & 63;
    int cg = (blk >> 6) & 7;
    int b  = blk >> 9;
    int h  = h4 * 4 + wid;
    int hm = (h == 0) ? 1 : h - 1;
    int hp = (h == Hd - 1) ? Hd - 2 : h + 1;

    // load + hamming-normalize the 4 positions' tap weights (view-scramble gather)
    float wv[4][9];
    {
        const float4* kv = (const float4*)(kw + (size_t)b * KK * HW
                                              + (size_t)h * (Wd * 9) + lane * 36);
        float t[36];
#pragma unroll
        for (int i = 0; i < 9; ++i) {
            float4 v = kv[i];
            t[i * 4 + 0] = v.x; t[i * 4 + 1] = v.y;
            t[i * 4 + 2] = v.z; t[i * 4 + 3] = v.w;
        }
#pragma unroll
        for (int j = 0; j < 4; ++j) {
            float s = 1e-8f;
#pragma unroll
            for (int p = 0; p < 9; ++p) { float u = t[j * 9 + p] * HAM[p]; wv[j][p] = u; s += u; }
            float inv = 1.f / s;
#pragma unroll
            for (int p = 0; p < 9; ++p) wv[j][p] *= inv;
        }
    }

    const float* xb = x + (size_t)b * Cd * HW;
    float* ob = out + (size_t)b * Cd * HW;
    int c0 = cg * CG;
    for (int c = c0; c < c0 + CG; ++c) {
        const float* xc0 = xb + (size_t)c * HW;
        float4 am = ((const float4*)(xc0 + hm * Wd))[lane];
        float4 ac = ((const float4*)(xc0 + h  * Wd))[lane];
        float4 ap = ((const float4*)(xc0 + hp * Wd))[lane];
        float Lm = __shfl_up(am.w, 1), Lc = __shfl_up(ac.w, 1), Lp = __shfl_up(ap.w, 1);
        float Rm = __shfl_down(am.x, 1), Rc = __shfl_down(ac.x, 1), Rp = __shfl_down(ap.x, 1);
        if (lane == 0)  { Lm = am.y; Lc = ac.y; Lp = ap.y; }   // reflect w=-1 -> w=1
        if (lane == 63) { Rm = am.z; Rc = ac.z; Rp = ap.z; }   // reflect w=256 -> w=254
        float em[6] = {Lm, am.x, am.y, am.z, am.w, Rm};
        float ec[6] = {Lc, ac.x, ac.y, ac.z, ac.w, Rc};
        float ep[6] = {Lp, ap.x, ap.y, ap.z, ap.w, Rp};
        float o4[4];
#pragma unroll
        for (int j = 0; j < 4; ++j) {
            float agg = em[j] * wv[j][0];
            agg = fmaf(em[j + 1], wv[j][1], agg);
            agg = fmaf(em[j + 2], wv[j][2], agg);
            agg = fmaf(ec[j],     wv[j][3], agg);
            agg = fmaf(ec[j + 1], wv[j][4], agg);
            agg = fmaf(ec[j + 2], wv[j][5], agg);
            agg = fmaf(ep[j],     wv[j][6], agg);
            agg = fmaf(ep[j + 1], wv[j][7], agg);
            agg = fmaf(ep[j + 2], wv[j][8], agg);
            o4[j] = 2.f * ec[j + 1] - agg;
        }
        float4 o = {o4[0], o4[1], o4[2], o4[3]};
        ((float4*)(ob + (size_t)c * HW + h * Wd))[lane] = o;
    }
}

extern "C" void kernel_launch(void* const* d_in, const int* in_sizes, int n_in,
                              void* d_out, int out_size, void* d_ws, size_t ws_size,
                              hipStream_t stream) {
    const float* x      = (const float*)d_in[0];
    const float* w_comp = (const float*)d_in[1];
    const float* w_gen  = (const float*)d_in[2];
    const float* b_gen  = (const float*)d_in[3];
    float* out  = (float*)d_out;
    float* comp = (float*)d_ws;                        // 4*64*65536 floats = 64 MiB
    float* kw   = comp + (size_t)Bd * CM * HW;         // 4*9*65536 floats = 9 MiB

    compress_kernel<<<2048, 256, 0, stream>>>(x, w_comp, comp);
    kwgen_kernel<<<1024, 256, 0, stream>>>(comp, w_gen, b_gen, kw);
    agg_kernel<<<2048, 256, 0, stream>>>(x, kw, out);
}

// Round 5
// 299.415 us; speedup vs baseline: 1.2890x; 1.2890x over previous
//
#include <hip/hip_runtime.h>
#include <stdint.h>

#define Bd 4
#define Cd 256
#define Hd 256
#define Wd 256
#define HW 65536
#define CM 64
#define KK 9
#define CG 32   // channels per wave in agg

// ---------------- Kernel A as MFMA GEMM: comp[o,s] = sum_c w[o,c] * x[c,s]
// M=64 (o), K=256 (c), N=262144 (b,s). bf16 inputs, fp32 accumulate.
// w staged once in LDS (bf16, 16B-granule XOR swizzle g^=o&7 -> conflict-free
// ds_read_b128 A-frags). x loaded directly from global per-lane (each element
// exactly once; no barriers, no lgkm/vm counter mixing in the K-loop).
// Round-4 lesson: keep live state small + statically indexed (pa/pb named bufs).

typedef __attribute__((ext_vector_type(8))) short bf16x8;
typedef __attribute__((ext_vector_type(4))) float f32x4;

__device__ __forceinline__ uint32_t f2bf1(float f) {
    uint32_t u = __float_as_uint(f);
    return (u + 0x7FFFu + ((u >> 16) & 1u)) >> 16;   // RNE to bf16
}
__device__ __forceinline__ uint32_t pkbf(float lo, float hi) {
    return f2bf1(lo) | (f2bf1(hi) << 16);
}

union BF8 { uint32_t u[4]; bf16x8 v; };

__device__ __forceinline__ void loadB(const float* __restrict__ px, int ks,
                                      float (&buf)[2][8]) {
#pragma unroll
    for (int n = 0; n < 2; ++n)
#pragma unroll
        for (int j = 0; j < 8; ++j)
            buf[n][j] = px[(size_t)(ks * 32 + j) * HW + n * 16];
}

__device__ __forceinline__ void stepMFMA(const float (&buf)[2][8],
                                         const short (*ws)[256], int ks,
                                         int l15, int lhi, int l7,
                                         f32x4 (&acc)[4][2]) {
    BF8 bn[2];
#pragma unroll
    for (int n = 0; n < 2; ++n) {
        bn[n].u[0] = pkbf(buf[n][0], buf[n][1]);
        bn[n].u[1] = pkbf(buf[n][2], buf[n][3]);
        bn[n].u[2] = pkbf(buf[n][4], buf[n][5]);
        bn[n].u[3] = pkbf(buf[n][6], buf[n][7]);
    }
#pragma unroll
    for (int m = 0; m < 4; ++m) {
        int gg = ((ks << 2) + lhi) ^ l7;                 // swizzled granule col
        bf16x8 af = *(const bf16x8*)&ws[m * 16 + l15][gg << 3];
        acc[m][0] = __builtin_amdgcn_mfma_f32_16x16x32_bf16(af, bn[0].v, acc[m][0], 0, 0, 0);
        acc[m][1] = __builtin_amdgcn_mfma_f32_16x16x32_bf16(af, bn[1].v, acc[m][1], 0, 0, 0);
    }
}

__global__ __launch_bounds__(256, 2) void compress_kernel(
    const float* __restrict__ x, const float* __restrict__ w_comp,
    float* __restrict__ comp)
{
    __shared__ short ws[CM][256];   // bf16 w, swizzled: granule g stored at g^(o&7)

    int tid = threadIdx.x;
    {   // stage w: thread t -> row o=t>>2, k-range (t&3)*64..+63 (coalesced)
        int o  = tid >> 2;
        int k0 = (tid & 3) << 6;
        const float* wr = w_comp + o * Cd + k0;
        int xr = o & 7;
#pragma unroll
        for (int gi = 0; gi < 8; ++gi) {
            float4 a = *(const float4*)(wr + gi * 8);
            float4 c = *(const float4*)(wr + gi * 8 + 4);
            BF8 g;
            g.u[0] = pkbf(a.x, a.y); g.u[1] = pkbf(a.z, a.w);
            g.u[2] = pkbf(c.x, c.y); g.u[3] = pkbf(c.z, c.w);
            int gg = ((k0 >> 3) + gi) ^ xr;
            *(bf16x8*)&ws[o][gg << 3] = g.v;
        }
    }
    __syncthreads();

    int lane = tid & 63;
    int wv   = tid >> 6;
    int blk  = blockIdx.x;            // 2048 blocks: [b(4)][s-tile(512)]
    int b    = blk >> 9;
    int s0   = ((blk & 511) << 7) + (wv << 5);   // wave: 32 s, all 64 o
    int l15  = lane & 15, lhi = lane >> 4, l7 = lane & 7;

    // B-frag element for lane: x[b][ks*32 + lhi*8 + j][s0 + n*16 + l15]
    const float* px = x + (size_t)b * Cd * HW + (size_t)(lhi * 8) * HW + s0 + l15;

    f32x4 acc[4][2];
    f32x4 zz = {0.f, 0.f, 0.f, 0.f};
#pragma unroll
    for (int m = 0; m < 4; ++m)
#pragma unroll
        for (int n = 0; n < 2; ++n) acc[m][n] = zz;

    float pa[2][8], pb[2][8];
    loadB(px, 0, pa);
    for (int ks = 0; ks < 8; ks += 2) {
        loadB(px, ks + 1, pb);                       // prefetch odd step
        stepMFMA(pa, ws, ks, l15, lhi, l7, acc);     // consume even step
        if (ks + 2 < 8) loadB(px, ks + 2, pa);       // prefetch next even
        stepMFMA(pb, ws, ks + 1, l15, lhi, l7, acc); // consume odd step
    }

    // D layout (m89-verified): col = lane&15, row = (lane>>4)*4 + reg
    float* ob = comp + (size_t)b * CM * HW + s0 + l15;
#pragma unroll
    for (int m = 0; m < 4; ++m)
#pragma unroll
        for (int n = 0; n < 2; ++n)
#pragma unroll
            for (int r = 0; r < 4; ++r)
                ob[(size_t)(m * 16 + lhi * 4 + r) * HW + n * 16] = acc[m][n][r];
}

// ---------------- Kernel B: 3x3 conv (zero pad) + bias + softmax over 9 taps
// One block = one (b,h) row; 4 waves cover 4 quarter-rows (lane-per-position).
// w_gen staged in LDS as wlds[c][t][12] (broadcast reads). Neighbors via shuffle.
__global__ __launch_bounds__(256) void kwgen_kernel(
    const float* __restrict__ comp, const float* __restrict__ w_gen,
    const float* __restrict__ b_gen, float* __restrict__ kw)
{
    __shared__ float wlds[CM][KK][12];
    // w_gen flat layout [t][c][3][3]: i = t*(CM*9) + c*9 + p
    for (int i = threadIdx.x; i < KK * CM * 9; i += 256) {
        int t = i / (CM * 9);
        int r = i - t * (CM * 9);
        int c = r / 9;
        int p = r - c * 9;
        wlds[c][t][p] = w_gen[i];
    }
    __syncthreads();

    int lane = threadIdx.x & 63;
    int q    = threadIdx.x >> 6;
    int b    = blockIdx.x >> 8;
    int h    = blockIdx.x & 255;
    int w    = q * 64 + lane;
    bool hmv = h > 0, hpv = h < Hd - 1;

    float acc[KK];
#pragma unroll
    for (int t = 0; t < KK; ++t) acc[t] = b_gen[t];

    const float* cb = comp + (size_t)b * CM * HW + h * Wd;
    for (int c = 0; c < CM; ++c) {
        const float* row = cb + (size_t)c * HW;
        float xm = hmv ? row[w - Wd] : 0.f;
        float xc = row[w];
        float xp = hpv ? row[w + Wd] : 0.f;
        float Lm = __shfl_up(xm, 1), Lc = __shfl_up(xc, 1), Lp = __shfl_up(xp, 1);
        float Rm = __shfl_down(xm, 1), Rc = __shfl_down(xc, 1), Rp = __shfl_down(xp, 1);
        if (lane == 0) {
            if (w == 0) { Lm = 0.f; Lc = 0.f; Lp = 0.f; }
            else {
                Lm = hmv ? row[w - 1 - Wd] : 0.f;
                Lc = row[w - 1];
                Lp = hpv ? row[w - 1 + Wd] : 0.f;
            }
        }
        if (lane == 63) {
            if (w == Wd - 1) { Rm = 0.f; Rc = 0.f; Rp = 0.f; }
            else {
                Rm = hmv ? row[w + 1 - Wd] : 0.f;
                Rc = row[w + 1];
                Rp = hpv ? row[w + 1 + Wd] : 0.f;
            }
        }
        float nb[9] = {Lm, xm, Rm, Lc, xc, Rc, Lp, xp, Rp};
#pragma unroll
        for (int t = 0; t < KK; ++t) {
            const float* wt = &wlds[c][t][0];
#pragma unroll
            for (int p = 0; p < 9; ++p)
                acc[t] = fmaf(nb[p], wt[p], acc[t]);
        }
    }
    // softmax over the 9 taps
    float m = acc[0];
#pragma unroll
    for (int t = 1; t < KK; ++t) m = fmaxf(m, acc[t]);
    float sum = 0.f;
#pragma unroll
    for (int t = 0; t < KK; ++t) { acc[t] = __expf(acc[t] - m); sum += acc[t]; }
    float inv = 1.f / sum;
    int s = h * Wd + w;
    float* ob = kw + (size_t)b * KK * HW + s;
#pragma unroll
    for (int t = 0; t < KK; ++t) ob[(size_t)t * HW] = acc[t] * inv;
}

// ---------------- Kernel C: view-scramble gather + hamming renorm + reflect aggregation
// Wave per (b, h, cgroup): lane covers 4 columns (float4); column neighbors via shuffle.
__global__ __launch_bounds__(256) void agg_kernel(
    const float* __restrict__ x, const float* __restrict__ kw,
    float* __restrict__ out)
{
    const float HAM[9] = {0.0064f, 0.08f, 0.0064f,
                          0.08f,   1.0f,  0.08f,
                          0.0064f, 0.08f, 0.0064f};
    int lane = threadIdx.x & 63;
    int wid  = threadIdx.x >> 6;
    int blk  = blockIdx.x;           // 2048 blocks: [b(4)][cg(8)][h4(64)]
    int h4 = blk & 63;
    int cg = (blk >> 6) & 7;
    int b  = blk >> 9;
    int h  = h4 * 4 + wid;
    int hm = (h == 0) ? 1 : h - 1;
    int hp = (h == Hd - 1) ? Hd - 2 : h + 1;

    // load + hamming-normalize the 4 positions' tap weights (view-scramble gather)
    float wv[4][9];
    {
        const float4* kv = (const float4*)(kw + (size_t)b * KK * HW
                                              + (size_t)h * (Wd * 9) + lane * 36);
        float t[36];
#pragma unroll
        for (int i = 0; i < 9; ++i) {
            float4 v = kv[i];
            t[i * 4 + 0] = v.x; t[i * 4 + 1] = v.y;
            t[i * 4 + 2] = v.z; t[i * 4 + 3] = v.w;
        }
#pragma unroll
        for (int j = 0; j < 4; ++j) {
            float s = 1e-8f;
#pragma unroll
            for (int p = 0; p < 9; ++p) { float u = t[j * 9 + p] * HAM[p]; wv[j][p] = u; s += u; }
            float inv = 1.f / s;
#pragma unroll
            for (int p = 0; p < 9; ++p) wv[j][p] *= inv;
        }
    }

    const float* xb = x + (size_t)b * Cd * HW;
    float* ob = out + (size_t)b * Cd * HW;
    int c0 = cg * CG;
    for (int c = c0; c < c0 + CG; ++c) {
        const float* xc0 = xb + (size_t)c * HW;
        float4 am = ((const float4*)(xc0 + hm * Wd))[lane];
        float4 ac = ((const float4*)(xc0 + h  * Wd))[lane];
        float4 ap = ((const float4*)(xc0 + hp * Wd))[lane];
        float Lm = __shfl_up(am.w, 1), Lc = __shfl_up(ac.w, 1), Lp = __shfl_up(ap.w, 1);
        float Rm = __shfl_down(am.x, 1), Rc = __shfl_down(ac.x, 1), Rp = __shfl_down(ap.x, 1);
        if (lane == 0)  { Lm = am.y; Lc = ac.y; Lp = ap.y; }   // reflect w=-1 -> w=1
        if (lane == 63) { Rm = am.z; Rc = ac.z; Rp = ap.z; }   // reflect w=256 -> w=254
        float em[6] = {Lm, am.x, am.y, am.z, am.w, Rm};
        float ec[6] = {Lc, ac.x, ac.y, ac.z, ac.w, Rc};
        float ep[6] = {Lp, ap.x, ap.y, ap.z, ap.w, Rp};
        float o4[4];
#pragma unroll
        for (int j = 0; j < 4; ++j) {
            float agg = em[j] * wv[j][0];
            agg = fmaf(em[j + 1], wv[j][1], agg);
            agg = fmaf(em[j + 2], wv[j][2], agg);
            agg = fmaf(ec[j],     wv[j][3], agg);
            agg = fmaf(ec[j + 1], wv[j][4], agg);
            agg = fmaf(ec[j + 2], wv[j][5], agg);
            agg = fmaf(ep[j],     wv[j][6], agg);
            agg = fmaf(ep[j + 1], wv[j][7], agg);
            agg = fmaf(ep[j + 2], wv[j][8], agg);
            o4[j] = 2.f * ec[j + 1] - agg;
        }
        float4 o = {o4[0], o4[1], o4[2], o4[3]};
        ((float4*)(ob + (size_t)c * HW + h * Wd))[lane] = o;
    }
}

extern "C" void kernel_launch(void* const* d_in, const int* in_sizes, int n_in,
                              void* d_out, int out_size, void* d_ws, size_t ws_size,
                              hipStream_t stream) {
    const float* x      = (const float*)d_in[0];
    const float* w_comp = (const float*)d_in[1];
    const float* w_gen  = (const float*)d_in[2];
    const float* b_gen  = (const float*)d_in[3];
    float* out  = (float*)d_out;
    float* comp = (float*)d_ws;                        // 4*64*65536 floats = 64 MiB
    float* kw   = comp + (size_t)Bd * CM * HW;         // 4*9*65536 floats = 9 MiB

    compress_kernel<<<2048, 256, 0, stream>>>(x, w_comp, comp);
    kwgen_kernel<<<1024, 256, 0, stream>>>(comp, w_gen, b_gen, kw);
    agg_kernel<<<2048, 256, 0, stream>>>(x, kw, out);
}